// Round 1
// baseline (574.504 us; speedup 1.0000x reference)
//
#include <hip/hip_runtime.h>
#include <cstdint>

#define NCLS 13
#define SMAX 10
#define PTHRESH 0.05f

// Exact (un-fused) squared distance, matching numpy's ((dx*dx + dy*dy) + dz*dz) in f32.
__device__ __forceinline__ float d2f(float ax, float ay, float az,
                                     float bx, float by, float bz) {
    float dx = ax - bx;
    float dy = ay - by;
    float dz = az - bz;
    return __fadd_rn(__fadd_rn(__fmul_rn(dx, dx), __fmul_rn(dy, dy)), __fmul_rn(dz, dz));
}

// Kernel A: softmax over classes, shifted coords (SoA), per-class valid count + first valid index.
__global__ void k_setup(const float* __restrict__ logits, const float* __restrict__ pts,
                        const float* __restrict__ offs, float* __restrict__ probs,
                        float* __restrict__ sx, float* __restrict__ sy, float* __restrict__ sz,
                        unsigned int* __restrict__ counts, unsigned int* __restrict__ firstv,
                        int N) {
    int b = blockIdx.y;
    int n = blockIdx.x * blockDim.x + threadIdx.x;
    if (n >= N) return;
    size_t bn = (size_t)b * N + n;
    const float* L = logits + bn * NCLS;
    float v[NCLS];
    float mx = -INFINITY;
#pragma unroll
    for (int c = 0; c < NCLS; ++c) { v[c] = L[c]; mx = fmaxf(mx, v[c]); }
    float s = 0.f;
#pragma unroll
    for (int c = 0; c < NCLS; ++c) { v[c] = expf(v[c] - mx); s += v[c]; }
    int lane = threadIdx.x & 63;
    int wave_base = n - lane;
#pragma unroll
    for (int c = 0; c < NCLS; ++c) {
        float p = v[c] / s;
        probs[((size_t)b * NCLS + c) * N + n] = p;
        unsigned long long m = __ballot(p > PTHRESH);
        if (lane == 0 && m) {
            atomicAdd(&counts[b * NCLS + c], (unsigned int)__popcll(m));
            atomicMin(&firstv[b * NCLS + c], (unsigned int)(wave_base + __ffsll(m) - 1));
        }
    }
    float x = pts[bn * 3 + 0] + offs[bn * 3 + 0];
    float y = pts[bn * 3 + 1] + offs[bn * 3 + 1];
    float z = pts[bn * 3 + 2] + offs[bn * 3 + 2];
    sx[bn] = x; sy[bn] = y; sz[bn] = z;
}

// Kernel B: deterministic FPS per (b, c). One 1024-thread block; mind[] lives in registers
// (64 per thread for N=65536). Argmax tie-break: smallest index (numpy first-occurrence).
__global__ __launch_bounds__(1024) void k_fps(
    const float* __restrict__ probs,
    const float* __restrict__ sx, const float* __restrict__ sy, const float* __restrict__ sz,
    const unsigned int* __restrict__ counts, const unsigned int* __restrict__ firstv,
    int* __restrict__ nseeds, float* __restrict__ seedxyz, int N) {
    int c = blockIdx.x, b = blockIdx.y;
    int bc = b * NCLS + c;
    int count = (int)counts[bc];
    int ns = min(SMAX, min(count / 50, count));
    if (threadIdx.x == 0) nseeds[bc] = ns;
    if (ns == 0) return;

    const float* px = sx + (size_t)b * N;
    const float* py = sy + (size_t)b * N;
    const float* pz = sz + (size_t)b * N;
    const float* pp = probs + (size_t)bc * N;

    int t = threadIdx.x;
    unsigned long long vm = 0ULL;
    float m[64];
#pragma unroll
    for (int j = 0; j < 64; ++j) {
        int n = t + (j << 10);
        if (pp[n] > PTHRESH) vm |= (1ULL << j);
        m[j] = INFINITY;
    }

    __shared__ float s_cx, s_cy, s_cz;
    __shared__ float s_rv[16];
    __shared__ int s_ri[16];

    if (t == 0) {
        int st = (int)firstv[bc];
        float x = px[st], y = py[st], z = pz[st];
        s_cx = x; s_cy = y; s_cz = z;
        float* sd = seedxyz + (size_t)bc * SMAX * 3;
        sd[0] = x; sd[1] = y; sd[2] = z;
    }
    __syncthreads();

    for (int s = 1; s < ns; ++s) {
        float cx = s_cx, cy = s_cy, cz = s_cz;
        float best = -INFINITY;
        int bidx = 0;
#pragma unroll
        for (int j = 0; j < 64; ++j) {
            int n = t + (j << 10);
            float d2 = d2f(px[n], py[n], pz[n], cx, cy, cz);
            float add = ((vm >> j) & 1ULL) ? 0.0f : -INFINITY;
            float nm = fminf(m[j], __fadd_rn(d2, add));
            m[j] = nm;
            if (nm > best) { best = nm; bidx = n; }  // strict > keeps first occurrence
        }
        // 64-lane butterfly argmax (val desc, idx asc)
#pragma unroll
        for (int off = 1; off < 64; off <<= 1) {
            float ov = __shfl_xor(best, off, 64);
            int oi = __shfl_xor(bidx, off, 64);
            if (ov > best || (ov == best && oi < bidx)) { best = ov; bidx = oi; }
        }
        int wv = t >> 6, lane = t & 63;
        if (lane == 0) { s_rv[wv] = best; s_ri[wv] = bidx; }
        __syncthreads();
        if (t == 0) {
            for (int w = 1; w < 16; ++w) {
                float ov = s_rv[w]; int oi = s_ri[w];
                if (ov > best || (ov == best && oi < bidx)) { best = ov; bidx = oi; }
            }
            float x = px[bidx], y = py[bidx], z = pz[bidx];
            s_cx = x; s_cy = y; s_cz = z;
            float* sd = seedxyz + ((size_t)bc * SMAX + s) * 3;
            sd[0] = x; sd[1] = y; sd[2] = z;
        }
        __syncthreads();
    }
}

// Kernel C: per point: Gaussian soft assignment per class, then softmax over K=130 instance
// rows (two passes, statically-indexed arrays only; skip max-subtraction since logits in [0,10]).
__global__ void k_out(const float* __restrict__ probs,
                      const float* __restrict__ sx, const float* __restrict__ sy,
                      const float* __restrict__ sz,
                      const int* __restrict__ nseeds, const float* __restrict__ seedxyz,
                      float* __restrict__ out, int N) {
    int b = blockIdx.y;
    int n = blockIdx.x * blockDim.x + threadIdx.x;
    __shared__ float S[NCLS * SMAX * 3];
    __shared__ int NSs[NCLS];
    int t = threadIdx.x;
    for (int i = t; i < NCLS * SMAX * 3; i += blockDim.x)
        S[i] = seedxyz[(size_t)b * NCLS * SMAX * 3 + i];
    if (t < NCLS) NSs[t] = nseeds[b * NCLS + t];
    __syncthreads();
    if (n >= N) return;

    size_t bn = (size_t)b * N + n;
    float x = sx[bn], y = sy[bn], z = sz[bn];
    float p[NCLS];
#pragma unroll
    for (int c = 0; c < NCLS; ++c) p[c] = probs[((size_t)b * NCLS + c) * N + n];

    float denom[NCLS];
    float sumexp = 0.f;
#pragma unroll
    for (int c = 0; c < NCLS; ++c) {
        int ns = NSs[c];
        denom[c] = 1.f;
        if (ns == 0) continue;
        float g = (p[c] > PTHRESH) ? p[c] : 0.f;
        float w[SMAX];
        float sw = 0.f;
#pragma unroll
        for (int s = 0; s < SMAX; ++s) {
            w[s] = 0.f;
            if (s < ns) {
                const float* sd = &S[(c * SMAX + s) * 3];
                float d2 = d2f(x, y, z, sd[0], sd[1], sd[2]);
                w[s] = expf(-d2 / 0.045f);
                sw += w[s];
            }
        }
        float den = sw + 1e-8f;
        denom[c] = den;
#pragma unroll
        for (int s = 0; s < SMAX; ++s) {
            if (s < ns) {
                float mval = (w[s] / den) * g;
                sumexp += expf(mval * 10.f);
            }
        }
    }

    float* ob = out + (size_t)b * (NCLS * SMAX) * N + n;
#pragma unroll
    for (int c = 0; c < NCLS; ++c) {
        int ns = NSs[c];
        float g = (p[c] > PTHRESH) ? p[c] : 0.f;
        float den = denom[c];
#pragma unroll
        for (int s = 0; s < SMAX; ++s) {
            float o = 0.f;
            if (s < ns) {
                const float* sd = &S[(c * SMAX + s) * 3];
                float d2 = d2f(x, y, z, sd[0], sd[1], sd[2]);
                float wv = expf(-d2 / 0.045f);
                float mval = (wv / den) * g;
                float e = expf(mval * 10.f);
                o = e / sumexp;
            }
            ob[(size_t)(c * SMAX + s) * N] = o;
        }
    }
}

extern "C" void kernel_launch(void* const* d_in, const int* in_sizes, int n_in,
                              void* d_out, int out_size, void* d_ws, size_t ws_size,
                              hipStream_t stream) {
    const float* logits = (const float*)d_in[0];
    const float* pts    = (const float*)d_in[1];
    const float* offs   = (const float*)d_in[2];
    float* out = (float*)d_out;

    const int B = 2;
    const int BN = in_sizes[0] / NCLS;   // B*N
    const int N = BN / B;                // 65536

    // Workspace layout
    char* w = (char*)d_ws;
    size_t off = 0;
    auto take = [&](size_t bytes) -> void* {
        void* p = w + off;
        off = (off + bytes + 255) & ~(size_t)255;
        return p;
    };
    float* probs   = (float*)take((size_t)B * NCLS * N * sizeof(float));
    float* sx      = (float*)take((size_t)B * N * sizeof(float));
    float* sy      = (float*)take((size_t)B * N * sizeof(float));
    float* sz      = (float*)take((size_t)B * N * sizeof(float));
    float* seedxyz = (float*)take((size_t)B * NCLS * SMAX * 3 * sizeof(float));
    unsigned int* counts = (unsigned int*)take(B * NCLS * sizeof(unsigned int));
    unsigned int* firstv = (unsigned int*)take(B * NCLS * sizeof(unsigned int));
    int* nseeds          = (int*)take(B * NCLS * sizeof(int));

    hipMemsetAsync(counts, 0x00, B * NCLS * sizeof(unsigned int), stream);
    hipMemsetAsync(firstv, 0xFF, B * NCLS * sizeof(unsigned int), stream);

    dim3 gA((N + 255) / 256, B);
    k_setup<<<gA, 256, 0, stream>>>(logits, pts, offs, probs, sx, sy, sz, counts, firstv, N);

    dim3 gB(NCLS, B);
    k_fps<<<gB, 1024, 0, stream>>>(probs, sx, sy, sz, counts, firstv, nseeds, seedxyz, N);

    dim3 gC((N + 255) / 256, B);
    k_out<<<gC, 256, 0, stream>>>(probs, sx, sy, sz, nseeds, seedxyz, out, N);
}